// Round 3
// baseline (255.206 us; speedup 1.0000x reference)
//
#include <hip/hip_runtime.h>
#include <hip/hip_bf16.h>
#include <stdint.h>

#define B_ 2
#define N_ 3000
#define F_ 64
#define H_ 4
#define D_ 32
#define K_ 128          // H_*D_ output feature cols
#define KT_ 9           // 9 k-tiles of 16 -> 144 cols (128 feat + 4 denom + 12 pad)
#define NCH_ 94         // ceil(3000/32) m-chunks (3008 padded)
#define NROWT_ 188      // ceil(3000/16) row tiles per batch

typedef short bf16x8 __attribute__((ext_vector_type(8)));
typedef float f32x4  __attribute__((ext_vector_type(4)));

__device__ __forceinline__ unsigned short f2bf(float f) {
    uint32_t x = __float_as_uint(f);
    return (unsigned short)((x + 0x7FFFu + ((x >> 16) & 1u)) >> 16);  // RNE
}

// ---- Pass 1: feat[b][h][n][d] = h . kernel ; e2[b][h][n] = feat . att_k2 ; node_mask
__global__ void k_feat(const float* __restrict__ hin, const float* __restrict__ kern,
                       const float* __restrict__ ak2,
                       float* __restrict__ feat, float* __restrict__ e2,
                       float* __restrict__ nmask) {
    int b = blockIdx.x / N_;
    int n = blockIdx.x % N_;
    __shared__ float hrow[F_];
    int tid = threadIdx.x;                       // 128 threads: (h = tid>>5, d = tid&31)
    if (tid < F_) hrow[tid] = hin[(size_t)(b * N_ + n) * F_ + tid];
    __syncthreads();
    int hh = tid >> 5, d = tid & 31;
    float acc = 0.f;
    #pragma unroll
    for (int f = 0; f < F_; ++f)
        acc = fmaf(hrow[f], kern[(hh * F_ + f) * D_ + d], acc);
    feat[((size_t)(b * H_ + hh) * N_ + n) * D_ + d] = acc;
    float v = acc * ak2[hh * D_ + d];
    #pragma unroll
    for (int o = 16; o >= 1; o >>= 1) v += __shfl_xor(v, o, 32);
    if (d == 0) e2[(size_t)(b * H_ + hh) * N_ + n] = v;
    unsigned long long bal = __ballot(tid < F_ && hrow[tid & (F_ - 1)] != 0.0f);
    if (tid == 0) nmask[b * N_ + n] = (bal != 0ull) ? 1.0f : 0.0f;
}

// ---- Pass 2: mx[b*H+h] = max_n e2
__global__ void k_max(const float* __restrict__ e2, float* __restrict__ mx) {
    int bh = blockIdx.x;
    int tid = threadIdx.x;
    float m = -1e30f;
    for (int i = tid; i < N_; i += 256) m = fmaxf(m, e2[(size_t)bh * N_ + i]);
    __shared__ float red[256];
    red[tid] = m; __syncthreads();
    for (int s = 128; s > 0; s >>= 1) {
        if (tid < s) red[tid] = fmaxf(red[tid], red[tid + s]);
        __syncthreads();
    }
    if (tid == 0) mx[bh] = red[0];
}

// ---- Pass 3: bit-pack adjacency (a != 0) -> bits[b][n][94 words], word w bit j = m = w*32+j
__global__ void k_bits(const float* __restrict__ a, uint32_t* __restrict__ bits) {
    int b = blockIdx.x / N_;
    int n = blockIdx.x % N_;
    const float* row = a + (size_t)(b * N_ + n) * N_;
    uint32_t* brow = bits + (size_t)(b * N_ + n) * NCH_;
    int wv = threadIdx.x >> 6, lane = threadIdx.x & 63;   // 256 thr = 4 waves
    for (int it = 0; it < 12; ++it) {
        int ig = wv * 12 + it;                            // 64-wide slab index, 0..46 valid
        if (ig < 47) {
            int m = ig * 64 + lane;
            float v = (m < N_) ? row[m] : 0.f;
            unsigned long long bal = __ballot(v != 0.f);
            if (lane == 0)  brow[ig * 2]     = (uint32_t)bal;
            if (lane == 32) brow[ig * 2 + 1] = (uint32_t)(bal >> 32);
        }
    }
}

// ---- Pass 4: G in MFMA-B-fragment order: G[((b*94+ch)*9+t)*64 + lane] = ushort8
//      lane: rg=lane>>4, col=lane&15 ; element j -> Gmat[m = ch*32+rg*8+j][k = t*16+col]
//      Gmat[m][k<128] = w[h][m]*feat[h][m][d] (h=k>>5,d=k&31); k in 128..131 -> w[k-128][m]; else 0
__global__ void k_G(const float* __restrict__ feat, const float* __restrict__ e2,
                    const float* __restrict__ mx, bf16x8* __restrict__ G) {
    int idx = blockIdx.x * blockDim.x + threadIdx.x;
    const int total = B_ * NCH_ * KT_ * 64;
    if (idx >= total) return;
    int lane = idx & 63;
    int t  = (idx >> 6) % KT_;
    int ch = ((idx >> 6) / KT_) % NCH_;
    int b  = idx / (64 * KT_ * NCH_);
    int rg = lane >> 4, col = lane & 15;
    int k  = t * 16 + col;
    int m0 = ch * 32 + rg * 8;
    float vals[8];
    if (k < K_ + H_) {
        int hh, d; bool wonly;
        if (k < K_) { hh = k >> 5; d = k & 31; wonly = false; }
        else        { hh = k - K_; d = 0;      wonly = true;  }
        float c = mx[b * H_ + hh];
        const float* e2p = e2 + (size_t)(b * H_ + hh) * N_;
        const float* fp  = feat + (size_t)(b * H_ + hh) * N_ * D_ + d;
        #pragma unroll
        for (int j = 0; j < 8; ++j) {
            int m = m0 + j;
            float v = 0.f;
            if (m < N_) {
                float w = __expf(e2p[m] - c);
                v = wonly ? w : w * fp[(size_t)m * D_];
            }
            vals[j] = v;
        }
    } else {
        #pragma unroll
        for (int j = 0; j < 8; ++j) vals[j] = 0.f;
    }
    union { bf16x8 v; unsigned short u[8]; } o;
    #pragma unroll
    for (int j = 0; j < 8; ++j) o.u[j] = f2bf(vals[j]);
    G[idx] = o.v;
}

// ---- Pass 5: main GEMM. 1 wave/block, 16 rows x 144 cols, reduce over 3008 m.
__global__ void __launch_bounds__(64) k_main(
        const uint32_t* __restrict__ bits, const bf16x8* __restrict__ G,
        const float* __restrict__ bias, const float* __restrict__ nmask,
        float* __restrict__ out) {
    int blk = blockIdx.x;
    int b  = blk / NROWT_;
    int rt = blk % NROWT_;
    int nbase = rt * 16;
    int l = threadIdx.x;
    int rg = l >> 4, col = l & 15;
    int arow = nbase + col;                       // A-frag row = lane&15
    int aclamp = min(arow, N_ - 1);
    const uint32_t* brow = bits + (size_t)(b * N_ + aclamp) * NCH_;
    const bf16x8* Gb = G + (size_t)b * NCH_ * KT_ * 64 + l;
    f32x4 acc[KT_];
    #pragma unroll
    for (int t = 0; t < KT_; ++t) acc[t] = (f32x4){0.f, 0.f, 0.f, 0.f};
    for (int ch = 0; ch < NCH_; ++ch) {
        uint32_t w  = brow[ch];
        uint32_t mb = (w >> (rg * 8)) & 0xFFu;
        union { uint32_t u[4]; bf16x8 v; } af;    // bf16 1.0 = 0x3F80, exact 0/1
        af.u[0] = ((mb & 1u)   ? 0x3F80u : 0u) | ((mb & 2u)   ? 0x3F800000u : 0u);
        af.u[1] = ((mb & 4u)   ? 0x3F80u : 0u) | ((mb & 8u)   ? 0x3F800000u : 0u);
        af.u[2] = ((mb & 16u)  ? 0x3F80u : 0u) | ((mb & 32u)  ? 0x3F800000u : 0u);
        af.u[3] = ((mb & 64u)  ? 0x3F80u : 0u) | ((mb & 128u) ? 0x3F800000u : 0u);
        const bf16x8* Gc = Gb + (size_t)ch * KT_ * 64;
        #pragma unroll
        for (int t = 0; t < KT_; ++t)
            acc[t] = __builtin_amdgcn_mfma_f32_16x16x32_bf16(af.v, Gc[t * 64], acc[t], 0, 0, 0);
    }
    // epilogue: tile 8 cols 0..3 hold denominators (head = col)
    __shared__ float dl[16][4];
    #pragma unroll
    for (int r = 0; r < 4; ++r)
        if (col < 4) dl[rg * 4 + r][col] = acc[8][r];
    __syncthreads();
    #pragma unroll
    for (int t = 0; t < 8; ++t) {
        int hh = t >> 1;
        float bk = bias[t * 16 + col];
        #pragma unroll
        for (int r = 0; r < 4; ++r) {
            int rowi = rg * 4 + r;                // D row = (lane>>4)*4 + reg
            int n = nbase + rowi;
            if (n < N_) {
                float den = dl[rowi][hh];
                float v = (den > 0.f) ? acc[t][r] / den : 0.f;
                v += bk;
                v = fmaxf(v, 0.f);
                v *= nmask[b * N_ + n];
                out[(size_t)(b * N_ + n) * K_ + t * 16 + col] = v;
            }
        }
    }
}

extern "C" void kernel_launch(void* const* d_in, const int* in_sizes, int n_in,
                              void* d_out, int out_size, void* d_ws, size_t ws_size,
                              hipStream_t stream) {
    const float* h    = (const float*)d_in[0];
    const float* a    = (const float*)d_in[1];
    const float* kern = (const float*)d_in[2];
    // d_in[3] = att_k1: cancels in row-softmax, unused
    const float* ak2  = (const float*)d_in[4];
    const float* bias = (const float*)d_in[5];
    float* out = (float*)d_out;

    char* ws = (char*)d_ws;
    size_t o_feat  = 0;                                   // 768000 f = 3,072,000 B
    size_t o_e2    = o_feat  + 3072000;                   //  24000 f =    96,000 B
    size_t o_mx    = o_e2    + 96000;                     //      8 f (pad 256)
    size_t o_nmask = o_mx    + 256;                       //   6000 f =  24,000 B (pad)
    size_t o_bits  = o_nmask + 24064;                     // 564000 u32 = 2,256,000 B (pad)
    size_t o_G     = o_bits  + 2256128;                   // 108288 * 16 B = 1,732,608 B
    float*    feat  = (float*)(ws + o_feat);
    float*    e2    = (float*)(ws + o_e2);
    float*    mx    = (float*)(ws + o_mx);
    float*    nmask = (float*)(ws + o_nmask);
    uint32_t* bits  = (uint32_t*)(ws + o_bits);
    bf16x8*   G     = (bf16x8*)(ws + o_G);

    k_feat<<<dim3(B_ * N_), dim3(128), 0, stream>>>(h, kern, ak2, feat, e2, nmask);
    k_max <<<dim3(B_ * H_), dim3(256), 0, stream>>>(e2, mx);
    k_bits<<<dim3(B_ * N_), dim3(256), 0, stream>>>(a, bits);
    int gtot = B_ * NCH_ * KT_ * 64;
    k_G   <<<dim3((gtot + 255) / 256), dim3(256), 0, stream>>>(feat, e2, mx, G);
    k_main<<<dim3(B_ * NROWT_), dim3(64), 0, stream>>>(bits, G, bias, nmask, out);
}

// Round 4
// 64.473 us; speedup vs baseline: 3.9584x; 3.9584x over previous
//
#include <hip/hip_runtime.h>
#include <hip/hip_bf16.h>
#include <stdint.h>

#define B_ 2
#define N_ 3000
#define F_ 64
#define H_ 4
#define D_ 32
#define K_ 128          // H_*D_ output feature cols
#define KT_ 9           // 9 k-tiles of 16 -> 144 cols (128 feat + 4 denom + 12 pad)
#define NCH_ 94         // ceil(3000/32) m-chunks (3008 padded)
#define NROWT_ 188      // ceil(3000/16) row tiles per batch

typedef short bf16x8 __attribute__((ext_vector_type(8)));
typedef float f32x4  __attribute__((ext_vector_type(4)));

__device__ __forceinline__ unsigned short f2bf(float f) {
    uint32_t x = __float_as_uint(f);
    return (unsigned short)((x + 0x7FFFu + ((x >> 16) & 1u)) >> 16);  // RNE
}

// ---- Pass 1: feat[b][h][n][d] = h . kernel ; e2[b][h][n] = feat . att_k2 ; node_mask
__global__ void k_feat(const float* __restrict__ hin, const float* __restrict__ kern,
                       const float* __restrict__ ak2,
                       float* __restrict__ feat, float* __restrict__ e2,
                       float* __restrict__ nmask) {
    int b = blockIdx.x / N_;
    int n = blockIdx.x % N_;
    __shared__ float hrow[F_];
    int tid = threadIdx.x;                       // 128 threads: (h = tid>>5, d = tid&31)
    if (tid < F_) hrow[tid] = hin[(size_t)(b * N_ + n) * F_ + tid];
    __syncthreads();
    int hh = tid >> 5, d = tid & 31;
    float acc = 0.f;
    #pragma unroll
    for (int f = 0; f < F_; ++f)
        acc = fmaf(hrow[f], kern[(hh * F_ + f) * D_ + d], acc);
    feat[((size_t)(b * H_ + hh) * N_ + n) * D_ + d] = acc;
    float v = acc * ak2[hh * D_ + d];
    #pragma unroll
    for (int o = 16; o >= 1; o >>= 1) v += __shfl_xor(v, o, 32);
    if (d == 0) e2[(size_t)(b * H_ + hh) * N_ + n] = v;
    unsigned long long bal = __ballot(tid < F_ && hrow[tid & (F_ - 1)] != 0.0f);
    if (tid == 0) nmask[b * N_ + n] = (bal != 0ull) ? 1.0f : 0.0f;
}

// ---- Pass 2: mx[b*H+h] = max_n e2
__global__ void k_max(const float* __restrict__ e2, float* __restrict__ mx) {
    int bh = blockIdx.x;
    int tid = threadIdx.x;
    float m = -1e30f;
    for (int i = tid; i < N_; i += 256) m = fmaxf(m, e2[(size_t)bh * N_ + i]);
    __shared__ float red[256];
    red[tid] = m; __syncthreads();
    for (int s = 128; s > 0; s >>= 1) {
        if (tid < s) red[tid] = fmaxf(red[tid], red[tid + s]);
        __syncthreads();
    }
    if (tid == 0) mx[bh] = red[0];
}

// ---- Pass 3: bit-pack adjacency (a != 0) -> bits[b][n][94 words], word w bit j = m = w*32+j
__global__ void k_bits(const float* __restrict__ a, uint32_t* __restrict__ bits) {
    int b = blockIdx.x / N_;
    int n = blockIdx.x % N_;
    const float* row = a + (size_t)(b * N_ + n) * N_;
    uint32_t* brow = bits + (size_t)(b * N_ + n) * NCH_;
    int wv = threadIdx.x >> 6, lane = threadIdx.x & 63;   // 256 thr = 4 waves
    for (int it = 0; it < 12; ++it) {
        int ig = wv * 12 + it;                            // 64-wide slab index, 0..46 valid
        if (ig < 47) {
            int m = ig * 64 + lane;
            float v = (m < N_) ? row[m] : 0.f;
            unsigned long long bal = __ballot(v != 0.f);
            if (lane == 0)  brow[ig * 2]     = (uint32_t)bal;
            if (lane == 32) brow[ig * 2 + 1] = (uint32_t)(bal >> 32);
        }
    }
}

// ---- Pass 4: G in MFMA-B-fragment order: G[((b*94+ch)*9+t)*64 + lane] = ushort8
//      lane: rg=lane>>4, col=lane&15 ; element j -> Gmat[m = ch*32+rg*8+j][k = t*16+col]
//      Gmat[m][k<128] = w[h][m]*feat[h][m][d] (h=k>>5,d=k&31); k in 128..131 -> w[k-128][m]; else 0
__global__ void k_G(const float* __restrict__ feat, const float* __restrict__ e2,
                    const float* __restrict__ mx, bf16x8* __restrict__ G) {
    int idx = blockIdx.x * blockDim.x + threadIdx.x;
    const int total = B_ * NCH_ * KT_ * 64;
    if (idx >= total) return;
    int lane = idx & 63;
    int t  = (idx >> 6) % KT_;
    int ch = ((idx >> 6) / KT_) % NCH_;
    int b  = idx / (64 * KT_ * NCH_);
    int rg = lane >> 4, col = lane & 15;
    int k  = t * 16 + col;
    int m0 = ch * 32 + rg * 8;
    float vals[8];
    if (k < K_ + H_) {
        int hh, d; bool wonly;
        if (k < K_) { hh = k >> 5; d = k & 31; wonly = false; }
        else        { hh = k - K_; d = 0;      wonly = true;  }
        float c = mx[b * H_ + hh];
        const float* e2p = e2 + (size_t)(b * H_ + hh) * N_;
        const float* fp  = feat + (size_t)(b * H_ + hh) * N_ * D_ + d;
        #pragma unroll
        for (int j = 0; j < 8; ++j) {
            int m = m0 + j;
            float v = 0.f;
            if (m < N_) {
                float w = __expf(e2p[m] - c);
                v = wonly ? w : w * fp[(size_t)m * D_];
            }
            vals[j] = v;
        }
    } else {
        #pragma unroll
        for (int j = 0; j < 8; ++j) vals[j] = 0.f;
    }
    union { bf16x8 v; unsigned short u[8]; } o;
    #pragma unroll
    for (int j = 0; j < 8; ++j) o.u[j] = f2bf(vals[j]);
    G[idx] = o.v;
}

// ---- Pass 5 helpers: register double-buffered load set + MFMA compute
__device__ __forceinline__ void loadset(const uint32_t* __restrict__ brow,
                                        const bf16x8* __restrict__ Gb, int ch,
                                        uint32_t& bw, bf16x8 (&g)[KT_]) {
    bw = brow[ch];
    const bf16x8* p = Gb + (size_t)ch * KT_ * 64;
    #pragma unroll
    for (int t = 0; t < KT_; ++t) g[t] = p[t * 64];
}

__device__ __forceinline__ void computeset(uint32_t bw, const bf16x8 (&g)[KT_],
                                           f32x4 (&acc)[KT_], int rg) {
    uint32_t mb = (bw >> (rg * 8)) & 0xFFu;
    union { uint32_t u[4]; bf16x8 v; } af;        // bf16 1.0 = 0x3F80, exact 0/1
    af.u[0] = ((mb & 1u)   ? 0x3F80u : 0u) | ((mb & 2u)   ? 0x3F800000u : 0u);
    af.u[1] = ((mb & 4u)   ? 0x3F80u : 0u) | ((mb & 8u)   ? 0x3F800000u : 0u);
    af.u[2] = ((mb & 16u)  ? 0x3F80u : 0u) | ((mb & 32u)  ? 0x3F800000u : 0u);
    af.u[3] = ((mb & 64u)  ? 0x3F80u : 0u) | ((mb & 128u) ? 0x3F800000u : 0u);
    #pragma unroll
    for (int t = 0; t < KT_; ++t)
        acc[t] = __builtin_amdgcn_mfma_f32_16x16x32_bf16(af.v, g[t], acc[t], 0, 0, 0);
}

// ---- Pass 5: main GEMM. 4 waves/block; each wave reduces ~24 of 94 m-chunks for the
//      same 16 rows x 144 cols; LDS cross-wave reduction + fused epilogue.
__global__ void __launch_bounds__(256) k_main(
        const uint32_t* __restrict__ bits, const bf16x8* __restrict__ G,
        const float* __restrict__ bias, const float* __restrict__ nmask,
        float* __restrict__ out) {
    int blk = blockIdx.x;
    int b  = blk / NROWT_;
    int rt = blk % NROWT_;
    int nbase = rt * 16;
    int w = threadIdx.x >> 6;                     // wave 0..3
    int l = threadIdx.x & 63;
    int rg = l >> 4, col = l & 15;
    int arow = nbase + col;                       // A-frag row = lane&15
    int aclamp = min(arow, N_ - 1);
    const uint32_t* brow = bits + (size_t)(b * N_ + aclamp) * NCH_;
    const bf16x8* Gb = G + (size_t)b * NCH_ * KT_ * 64 + l;

    // wave w's chunk range: 24,24,23,23
    int c0 = (w < 2) ? w * 24 : 48 + (w - 2) * 23;
    int c1 = c0 + ((w < 2) ? 24 : 23);

    f32x4 acc[KT_];
    #pragma unroll
    for (int t = 0; t < KT_; ++t) acc[t] = (f32x4){0.f, 0.f, 0.f, 0.f};

    // software pipeline: prefetch set B while computing set A (all loads of a set in flight)
    uint32_t bwA, bwB;
    bf16x8 gA[KT_], gB[KT_];
    loadset(brow, Gb, c0, bwA, gA);
    int ch = c0;
    for (;;) {
        if (ch + 1 < c1) loadset(brow, Gb, ch + 1, bwB, gB);
        computeset(bwA, gA, acc, rg);
        if (++ch >= c1) break;
        if (ch + 1 < c1) loadset(brow, Gb, ch + 1, bwA, gA);
        computeset(bwB, gB, acc, rg);
        if (++ch >= c1) break;
    }

    // cross-wave reduction in LDS
    __shared__ float red[4][KT_ * 4][64];         // 36,864 B
    __shared__ float dl[16][4];
    #pragma unroll
    for (int t = 0; t < KT_; ++t)
        #pragma unroll
        for (int r = 0; r < 4; ++r)
            red[w][t * 4 + r][l] = acc[t][r];
    __syncthreads();

    // denominators from tile 8, cols 0..3: value (r, lane=(rg<<4)|hh) -> row rg*4+r, head hh
    if (threadIdx.x < 64) {
        int rowi = threadIdx.x >> 2;              // 0..15
        int hh   = threadIdx.x & 3;               // 0..3
        int rg2 = rowi >> 2, r2 = rowi & 3;
        int lane2 = (rg2 << 4) | hh;
        dl[rowi][hh] = red[0][32 + r2][lane2] + red[1][32 + r2][lane2]
                     + red[2][32 + r2][lane2] + red[3][32 + r2][lane2];
    }
    __syncthreads();

    // outputs: tiles 0..7 (32 t4r combos x 64 lanes), 8 per thread
    #pragma unroll
    for (int i = 0; i < 8; ++i) {
        int t4r = w + i * 4;                      // 0..31
        int t = t4r >> 2, r = t4r & 3;
        int rowi = rg * 4 + r;                    // D row = (lane>>4)*4 + reg
        int n = nbase + rowi;
        if (n < N_) {
            float s = red[0][t4r][l] + red[1][t4r][l] + red[2][t4r][l] + red[3][t4r][l];
            int hh = t >> 1;
            float den = dl[rowi][hh];
            float v = (den > 0.f) ? s / den : 0.f;
            v += bias[t * 16 + col];
            v = fmaxf(v, 0.f);
            v *= nmask[b * N_ + n];
            out[(size_t)(b * N_ + n) * K_ + t * 16 + col] = v;
        }
    }
}

extern "C" void kernel_launch(void* const* d_in, const int* in_sizes, int n_in,
                              void* d_out, int out_size, void* d_ws, size_t ws_size,
                              hipStream_t stream) {
    const float* h    = (const float*)d_in[0];
    const float* a    = (const float*)d_in[1];
    const float* kern = (const float*)d_in[2];
    // d_in[3] = att_k1: cancels in row-softmax, unused
    const float* ak2  = (const float*)d_in[4];
    const float* bias = (const float*)d_in[5];
    float* out = (float*)d_out;

    char* ws = (char*)d_ws;
    size_t o_feat  = 0;                                   // 768000 f = 3,072,000 B
    size_t o_e2    = o_feat  + 3072000;                   //  24000 f =    96,000 B
    size_t o_mx    = o_e2    + 96000;                     //      8 f (pad 256)
    size_t o_nmask = o_mx    + 256;                       //   6000 f =  24,000 B (pad)
    size_t o_bits  = o_nmask + 24064;                     // 564000 u32 = 2,256,000 B (pad)
    size_t o_G     = o_bits  + 2256128;                   // 108288 * 16 B = 1,732,608 B
    float*    feat  = (float*)(ws + o_feat);
    float*    e2    = (float*)(ws + o_e2);
    float*    mx    = (float*)(ws + o_mx);
    float*    nmask = (float*)(ws + o_nmask);
    uint32_t* bits  = (uint32_t*)(ws + o_bits);
    bf16x8*   G     = (bf16x8*)(ws + o_G);

    k_feat<<<dim3(B_ * N_), dim3(128), 0, stream>>>(h, kern, ak2, feat, e2, nmask);
    k_max <<<dim3(B_ * H_), dim3(256), 0, stream>>>(e2, mx);
    k_bits<<<dim3(B_ * N_), dim3(256), 0, stream>>>(a, bits);
    int gtot = B_ * NCH_ * KT_ * 64;
    k_G   <<<dim3((gtot + 255) / 256), dim3(256), 0, stream>>>(feat, e2, mx, G);
    k_main<<<dim3(B_ * NROWT_), dim3(256), 0, stream>>>(bits, G, bias, nmask, out);
}

// Round 5
// 49.801 us; speedup vs baseline: 5.1245x; 1.2946x over previous
//
#include <hip/hip_runtime.h>
#include <hip/hip_bf16.h>
#include <stdint.h>

#define B_ 2
#define N_ 3000
#define F_ 64
#define H_ 4
#define D_ 32
#define K_ 128          // H_*D_ output feature cols
#define KT_ 9           // 9 k-tiles of 16 -> 144 cols (128 feat + 4 denom + 12 pad)
#define NCH_ 94         // ceil(3000/32) m-chunks (3008 padded)
#define NROWT_ 188      // ceil(3000/16) row tiles per batch

typedef short bf16x8 __attribute__((ext_vector_type(8)));
typedef float f32x4  __attribute__((ext_vector_type(4)));

__device__ __forceinline__ unsigned short f2bf(float f) {
    uint32_t x = __float_as_uint(f);
    return (unsigned short)((x + 0x7FFFu + ((x >> 16) & 1u)) >> 16);  // RNE
}

// ---- Pass 1: feat[b][h][n][d] = h . kernel ; e2[b][h][n] = feat . att_k2 ; node_mask
__global__ void k_feat(const float* __restrict__ hin, const float* __restrict__ kern,
                       const float* __restrict__ ak2,
                       float* __restrict__ feat, float* __restrict__ e2,
                       float* __restrict__ nmask) {
    int b = blockIdx.x / N_;
    int n = blockIdx.x % N_;
    __shared__ float hrow[F_];
    int tid = threadIdx.x;                       // 128 threads: (h = tid>>5, d = tid&31)
    if (tid < F_) hrow[tid] = hin[(size_t)(b * N_ + n) * F_ + tid];
    __syncthreads();
    int hh = tid >> 5, d = tid & 31;
    float acc = 0.f;
    #pragma unroll
    for (int f = 0; f < F_; ++f)
        acc = fmaf(hrow[f], kern[(hh * F_ + f) * D_ + d], acc);
    feat[((size_t)(b * H_ + hh) * N_ + n) * D_ + d] = acc;
    float v = acc * ak2[hh * D_ + d];
    #pragma unroll
    for (int o = 16; o >= 1; o >>= 1) v += __shfl_xor(v, o, 32);
    if (d == 0) e2[(size_t)(b * H_ + hh) * N_ + n] = v;
    unsigned long long bal = __ballot(tid < F_ && hrow[tid & (F_ - 1)] != 0.0f);
    if (tid == 0) nmask[b * N_ + n] = (bal != 0ull) ? 1.0f : 0.0f;
}

// ---- Pass 2: G in MFMA-B-fragment order: G[((b*94+ch)*9+t)*64 + lane] = ushort8
//      lane: rg=lane>>4, col=lane&15 ; element j -> Gmat[m = ch*32+rg*8+j][k = t*16+col]
//      Gmat[m][k<128] = w[h][m]*feat[h][m][d] (h=k>>5,d=k&31); k in 128..131 -> w[k-128][m]; else 0
//      w[h][m] = exp(e2[h][m])  (max-subtraction cancels in the ratio; |e2|~O(1) so no overflow)
__global__ void k_G(const float* __restrict__ feat, const float* __restrict__ e2,
                    bf16x8* __restrict__ G) {
    int idx = blockIdx.x * blockDim.x + threadIdx.x;
    const int total = B_ * NCH_ * KT_ * 64;
    if (idx >= total) return;
    int lane = idx & 63;
    int t  = (idx >> 6) % KT_;
    int ch = ((idx >> 6) / KT_) % NCH_;
    int b  = idx / (64 * KT_ * NCH_);
    int rg = lane >> 4, col = lane & 15;
    int k  = t * 16 + col;
    int m0 = ch * 32 + rg * 8;
    float vals[8];
    if (k < K_ + H_) {
        int hh, d; bool wonly;
        if (k < K_) { hh = k >> 5; d = k & 31; wonly = false; }
        else        { hh = k - K_; d = 0;      wonly = true;  }
        const float* e2p = e2 + (size_t)(b * H_ + hh) * N_;
        const float* fp  = feat + (size_t)(b * H_ + hh) * N_ * D_ + d;
        #pragma unroll
        for (int j = 0; j < 8; ++j) {
            int m = m0 + j;
            float v = 0.f;
            if (m < N_) {
                float w = __expf(e2p[m]);
                v = wonly ? w : w * fp[(size_t)m * D_];
            }
            vals[j] = v;
        }
    } else {
        #pragma unroll
        for (int j = 0; j < 8; ++j) vals[j] = 0.f;
    }
    union { bf16x8 v; unsigned short u[8]; } o;
    #pragma unroll
    for (int j = 0; j < 8; ++j) o.u[j] = f2bf(vals[j]);
    G[idx] = o.v;
}

// ---- Pass 3 helpers: register double-buffered load set + MFMA compute.
//      A-fragment comes straight from adjacency floats: lane (row=l&15) loads
//      a[row][ch*32 + rg*8 .. +7] as two float4s (32B contiguous, 16B-aligned since
//      row stride 12000B and chunk offset 128B are both /16).
__device__ __forceinline__ void loadsetA(const float* __restrict__ arow, int ch, int rg,
                                         f32x4& f0, f32x4& f1) {
    if (ch == NCH_ - 1 && rg == 3) {              // m=3000..3007: out of range
        f0 = (f32x4){0.f, 0.f, 0.f, 0.f};
        f1 = (f32x4){0.f, 0.f, 0.f, 0.f};
    } else {
        const f32x4* p = (const f32x4*)(arow + ch * 32 + rg * 8);
        f0 = p[0]; f1 = p[1];
    }
}

__device__ __forceinline__ void loadsetG(const bf16x8* __restrict__ Gb, int ch,
                                         bf16x8 (&g)[KT_]) {
    const bf16x8* p = Gb + (size_t)ch * KT_ * 64;
    #pragma unroll
    for (int t = 0; t < KT_; ++t) g[t] = p[t * 64];
}

__device__ __forceinline__ void computeset(const f32x4& f0, const f32x4& f1,
                                           const bf16x8 (&g)[KT_], f32x4 (&acc)[KT_]) {
    union { uint32_t u[4]; bf16x8 v; } af;        // bf16 1.0 = 0x3F80, exact 0/1
    af.u[0] = ((f0.x != 0.f) ? 0x3F80u : 0u) | ((f0.y != 0.f) ? 0x3F800000u : 0u);
    af.u[1] = ((f0.z != 0.f) ? 0x3F80u : 0u) | ((f0.w != 0.f) ? 0x3F800000u : 0u);
    af.u[2] = ((f1.x != 0.f) ? 0x3F80u : 0u) | ((f1.y != 0.f) ? 0x3F800000u : 0u);
    af.u[3] = ((f1.z != 0.f) ? 0x3F80u : 0u) | ((f1.w != 0.f) ? 0x3F800000u : 0u);
    #pragma unroll
    for (int t = 0; t < KT_; ++t)
        acc[t] = __builtin_amdgcn_mfma_f32_16x16x32_bf16(af.v, g[t], acc[t], 0, 0, 0);
}

// ---- Pass 3: main GEMM, adjacency read fused. 4 waves/block; each wave reduces
//      ~24 of 94 m-chunks for the same 16 rows x 144 cols; LDS cross-wave reduction
//      + fused softmax-divide/bias/relu/mask epilogue.
__global__ void __launch_bounds__(256) k_main(
        const float* __restrict__ a, const bf16x8* __restrict__ G,
        const float* __restrict__ bias, const float* __restrict__ nmask,
        float* __restrict__ out) {
    int blk = blockIdx.x;
    int b  = blk / NROWT_;
    int rt = blk % NROWT_;
    int nbase = rt * 16;
    int w = threadIdx.x >> 6;                     // wave 0..3
    int l = threadIdx.x & 63;
    int rg = l >> 4, col = l & 15;
    int arow_i = nbase + col;                     // A-frag row = lane&15
    int aclamp = min(arow_i, N_ - 1);
    const float* arow = a + (size_t)(b * N_ + aclamp) * N_;
    const bf16x8* Gb = G + (size_t)b * NCH_ * KT_ * 64 + l;

    // wave w's chunk range: 24,24,23,23
    int c0 = (w < 2) ? w * 24 : 48 + (w - 2) * 23;
    int c1 = c0 + ((w < 2) ? 24 : 23);

    f32x4 acc[KT_];
    #pragma unroll
    for (int t = 0; t < KT_; ++t) acc[t] = (f32x4){0.f, 0.f, 0.f, 0.f};

    // software pipeline: prefetch set B while computing set A (all 11 loads of a set in flight)
    f32x4 aA0, aA1, aB0, aB1;
    bf16x8 gA[KT_], gB[KT_];
    loadsetA(arow, c0, rg, aA0, aA1);
    loadsetG(Gb, c0, gA);
    int ch = c0;
    for (;;) {
        if (ch + 1 < c1) { loadsetA(arow, ch + 1, rg, aB0, aB1); loadsetG(Gb, ch + 1, gB); }
        computeset(aA0, aA1, gA, acc);
        if (++ch >= c1) break;
        if (ch + 1 < c1) { loadsetA(arow, ch + 1, rg, aA0, aA1); loadsetG(Gb, ch + 1, gA); }
        computeset(aB0, aB1, gB, acc);
        if (++ch >= c1) break;
    }

    // cross-wave reduction in LDS
    __shared__ float red[4][KT_ * 4][64];         // 36,864 B
    __shared__ float dl[16][4];
    #pragma unroll
    for (int t = 0; t < KT_; ++t)
        #pragma unroll
        for (int r = 0; r < 4; ++r)
            red[w][t * 4 + r][l] = acc[t][r];
    __syncthreads();

    // denominators from tile 8, cols 0..3: value (r, lane=(rg<<4)|hh) -> row rg*4+r, head hh
    if (threadIdx.x < 64) {
        int rowi = threadIdx.x >> 2;              // 0..15
        int hh   = threadIdx.x & 3;               // 0..3
        int rg2 = rowi >> 2, r2 = rowi & 3;
        int lane2 = (rg2 << 4) | hh;
        dl[rowi][hh] = red[0][32 + r2][lane2] + red[1][32 + r2][lane2]
                     + red[2][32 + r2][lane2] + red[3][32 + r2][lane2];
    }
    __syncthreads();

    // outputs: tiles 0..7 (32 t4r combos x 64 lanes), 8 per thread
    #pragma unroll
    for (int i = 0; i < 8; ++i) {
        int t4r = w + i * 4;                      // 0..31
        int t = t4r >> 2, r = t4r & 3;
        int rowi = rg * 4 + r;                    // D row = (lane>>4)*4 + reg
        int n = nbase + rowi;
        if (n < N_) {
            float s = red[0][t4r][l] + red[1][t4r][l] + red[2][t4r][l] + red[3][t4r][l];
            int hh = t >> 1;
            float den = dl[rowi][hh];
            float v = (den > 0.f) ? s / den : 0.f;
            v += bias[t * 16 + col];
            v = fmaxf(v, 0.f);
            v *= nmask[b * N_ + n];
            out[(size_t)(b * N_ + n) * K_ + t * 16 + col] = v;
        }
    }
}

extern "C" void kernel_launch(void* const* d_in, const int* in_sizes, int n_in,
                              void* d_out, int out_size, void* d_ws, size_t ws_size,
                              hipStream_t stream) {
    const float* h    = (const float*)d_in[0];
    const float* a    = (const float*)d_in[1];
    const float* kern = (const float*)d_in[2];
    // d_in[3] = att_k1: cancels in row-softmax, unused
    const float* ak2  = (const float*)d_in[4];
    const float* bias = (const float*)d_in[5];
    float* out = (float*)d_out;

    char* ws = (char*)d_ws;
    size_t o_feat  = 0;                                   // 768000 f = 3,072,000 B
    size_t o_e2    = o_feat  + 3072000;                   //  24000 f =    96,000 B
    size_t o_nmask = o_e2    + 96000;                     //   6000 f =  24,000 B (pad)
    size_t o_G     = o_nmask + 24064;                     // 108288 * 16 B = 1,732,608 B
    float*  feat  = (float*)(ws + o_feat);
    float*  e2    = (float*)(ws + o_e2);
    float*  nmask = (float*)(ws + o_nmask);
    bf16x8* G     = (bf16x8*)(ws + o_G);

    k_feat<<<dim3(B_ * N_), dim3(128), 0, stream>>>(h, kern, ak2, feat, e2, nmask);
    int gtot = B_ * NCH_ * KT_ * 64;
    k_G   <<<dim3((gtot + 255) / 256), dim3(256), 0, stream>>>(feat, e2, G);
    k_main<<<dim3(B_ * NROWT_), dim3(256), 0, stream>>>(a, G, bias, nmask, out);
}